// Round 5
// baseline (270.620 us; speedup 1.0000x reference)
//
#include <hip/hip_runtime.h>
#include <stdint.h>

typedef __attribute__((ext_vector_type(8))) short bf16x8;
typedef __attribute__((ext_vector_type(4))) float f32x4;

#define HH  100   // history length
#define DD  128   // embedding dim d
#define HID 256   // hidden width / concat dim

__device__ __forceinline__ unsigned short f2bf(float f) {
    unsigned int u = __float_as_uint(f);
    u += 0x7fffu + ((u >> 16) & 1u);   // round-to-nearest-even
    return (unsigned short)(u >> 16);
}

// async 1 KB global->LDS per wave: per-lane 16 B from g+lane*16, LDS at uniform base l + lane*16
__device__ __forceinline__ void load_lds_1k(const void* g, void* l) {
    __builtin_amdgcn_global_load_lds((const __attribute__((address_space(1))) unsigned int*)g,
                                     (__attribute__((address_space(3))) unsigned int*)l,
                                     16, 0, 0);
}

// Pack W1 (256x256 f32, [n][k]) into MFMA B-fragment order, bf16.
// unit = (st*8+s)*64 + lane holds W1[st*16 + (lane&15)][s*32 + (lane>>4)*8 + j], j=0..7
__global__ void w1_pack(const float* __restrict__ W1, unsigned short* __restrict__ W1p) {
    int unit = blockIdx.x * 256 + threadIdx.x;   // 0..8191
    int lane = unit & 63;
    int s    = (unit >> 6) & 7;
    int st   = unit >> 9;
    int col  = lane & 15, quad = lane >> 4;
    const float* src = W1 + (size_t)(st * 16 + col) * HID + s * 32 + quad * 8;
    union { unsigned short u[8]; bf16x8 v; } o;
    #pragma unroll
    for (int j = 0; j < 8; j++) o.u[j] = f2bf(src[j]);
    *(bf16x8*)(W1p + (size_t)unit * 8) = o.v;
}

__global__ __launch_bounds__(256, 3) void nais_kernel(
    const int* __restrict__ history,           // [B,HH]
    const int* __restrict__ target,            // [B]
    const int* __restrict__ history_region,    // [B,HH]
    const int* __restrict__ target_region,     // [B]
    const float* __restrict__ target_distance, // [B]
    const float* __restrict__ E_hist,          // [item,128]
    const float* __restrict__ E_tgt,           // [item,128]
    const float* __restrict__ E_reg,           // [region,128]
    const float* __restrict__ E_dist,          // [16,128]
    const float* __restrict__ b1,              // [256]
    const float* __restrict__ w2,              // [256]
    const unsigned short* __restrict__ W1p,    // packed bf16 B-fragments (128 KB)
    float* __restrict__ out)                   // [B]
{
    // B-stage: 8 stages x 16 KB (2 st-strips), double-buffered
    __shared__ __align__(16) unsigned short Bs[2][8192];  // 32 KB
    __shared__ __align__(16) float tgts[HID];
    __shared__ __align__(16) float b1s[HID];
    __shared__ __align__(16) float w2s[HID];
    __shared__ float score[128];
    __shared__ float xsum[HH];
    __shared__ float eA[HH];
    __shared__ float exs[HH];
    __shared__ int hidx[HH];
    __shared__ int hreg[HH];
    __shared__ float s_sumE;

    const int b    = blockIdx.x;
    const int t    = threadIdx.x;
    const int lane = t & 63;
    const int wave = t >> 6;
    const int col  = lane & 15;
    const int quad = lane >> 4;

    const int   tg    = target[b];
    const float tdist = target_distance[b];

    // ---- phase 0: stage indices, tgt vector, b1/w2, sum(E_dist[0]) ----
    if (t < HH) {
        hidx[t] = history[b * HH + t];
        hreg[t] = history_region[b * HH + t];
    }
    if (wave == 1) {
        float v = E_dist[lane] + E_dist[64 + lane];
        #pragma unroll
        for (int off = 32; off; off >>= 1) v += __shfl_xor(v, off);
        if (lane == 0) s_sumE = v;
    }
    if (wave == 2) {
        float4 v;
        if (lane < 32) v = *(const float4*)(E_tgt + (size_t)tg * DD + lane * 4);
        else           v = *(const float4*)(E_reg + (size_t)target_region[b] * DD + (lane - 32) * 4);
        *(float4*)(tgts + lane * 4) = v;
    }
    if (wave == 3) {
        *(float4*)(b1s + lane * 4) = *(const float4*)(b1 + lane * 4);
        *(float4*)(w2s + lane * 4) = *(const float4*)(w2 + lane * 4);
    }
    __syncthreads();

    // issue stage-0 B load (async; overlaps the gather phase)
    {
        const char* g = (const char*)W1p + wave * 4096 + lane * 16;
        char*       l = (char*)&Bs[0][0] + wave * 4096;
        #pragma unroll
        for (int i = 0; i < 4; i++) load_lds_1k(g + i * 1024, l + i * 1024);
    }

    // ---- phase 1: gather E-rows directly into MFMA A-fragment layout ----
    // wave w owns rows [32w, 32w+32): m-tiles mt in {0,1}, row = 32w + mt*16 + col.
    // A-frag element: lane(col,quad), k = s*32 + quad*8 + j  (s<4: E_hist, s>=4: E_reg)
    bf16x8 afrag[2][8];
    float xs[2];
    #pragma unroll
    for (int mt = 0; mt < 2; mt++) {
        const int  row   = wave * 32 + mt * 16 + col;
        const bool valid = row < HH;
        const int  rc    = valid ? row : 0;
        const int  ih    = hidx[rc];
        const int  ir    = hreg[rc];
        const float* ph  = E_hist + (size_t)ih * DD + quad * 8;
        const float* pr  = E_reg  + (size_t)ir * DD + quad * 8;
        float acc = 0.f;
        #pragma unroll
        for (int s = 0; s < 8; s++) {
            const float* src = (s < 4) ? (ph + s * 32) : (pr + (s - 4) * 32);
            float4 v0 = {0.f, 0.f, 0.f, 0.f}, v1 = {0.f, 0.f, 0.f, 0.f};
            if (valid) { v0 = *(const float4*)src; v1 = *(const float4*)(src + 4); }
            const float* tp = tgts + s * 32 + quad * 8;      // broadcast across cols
            float4 t0 = *(const float4*)tp, t1 = *(const float4*)(tp + 4);
            float x0 = v0.x * t0.x, x1 = v0.y * t0.y, x2 = v0.z * t0.z, x3 = v0.w * t0.w;
            float x4 = v1.x * t1.x, x5 = v1.y * t1.y, x6 = v1.z * t1.z, x7 = v1.w * t1.w;
            acc += (x0 + x1) + (x2 + x3) + ((x4 + x5) + (x6 + x7));
            union { unsigned short u[8]; bf16x8 v; } fb;
            fb.u[0] = f2bf(x0); fb.u[1] = f2bf(x1); fb.u[2] = f2bf(x2); fb.u[3] = f2bf(x3);
            fb.u[4] = f2bf(x4); fb.u[5] = f2bf(x5); fb.u[6] = f2bf(x6); fb.u[7] = f2bf(x7);
            afrag[mt][s] = fb.v;
        }
        xs[mt] = acc;
        // scheduling fence: cap in-flight gather loads at 16 float4 (64 VGPRs)
        asm volatile("" ::: "memory");
    }
    // xsum[row] = sum over k: reduce across the 4 quads (lane bits 4,5)
    #pragma unroll
    for (int mt = 0; mt < 2; mt++) {
        float v = xs[mt];
        v += __shfl_xor(v, 16);
        v += __shfl_xor(v, 32);
        const int row = wave * 32 + mt * 16 + col;
        if (quad == 0 && row < HH) xsum[row] = v;
    }

    // ---- phase 2: score = relu(X @ W1^T + b1) . w2 via MFMA, B staged thru LDS ----
    // stage k holds st in {2k, 2k+1}; barrier-per-stage double buffer:
    //   barrier -> issue(k+1) into buf[(k+1)&1] -> compute(k) from buf[k&1]
    float sacc[2][4] = {};
    #pragma unroll 1
    for (int k = 0; k < 8; k++) {
        __syncthreads();   // stage-k data visible (compiler drains vmcnt before barrier);
                           // all waves done reading buf[(k+1)&1] from stage k-1
        if (k < 7) {
            const char* g = (const char*)W1p + (k + 1) * 16384 + wave * 4096 + lane * 16;
            char*       l = (char*)&Bs[(k + 1) & 1][0] + wave * 4096;
            #pragma unroll
            for (int i = 0; i < 4; i++) load_lds_1k(g + i * 1024, l + i * 1024);
        }
        const unsigned short* buf = &Bs[k & 1][0];
        #pragma unroll
        for (int sti = 0; sti < 2; sti++) {
            const int st = k * 2 + sti;
            const float bb = b1s[st * 16 + col];
            const float ww = w2s[st * 16 + col];
            f32x4 acc0 = {0.f, 0.f, 0.f, 0.f};
            f32x4 acc1 = {0.f, 0.f, 0.f, 0.f};
            #pragma unroll
            for (int s = 0; s < 8; s++) {
                bf16x8 bfrag = *(const bf16x8*)(buf + ((sti * 8 + s) * 64 + lane) * 8);
                acc0 = __builtin_amdgcn_mfma_f32_16x16x32_bf16(afrag[0][s], bfrag, acc0, 0, 0, 0);
                acc1 = __builtin_amdgcn_mfma_f32_16x16x32_bf16(afrag[1][s], bfrag, acc1, 0, 0, 0);
            }
            #pragma unroll
            for (int r = 0; r < 4; r++) {
                float z0 = acc0[r] + bb; sacc[0][r] += (z0 > 0.f) ? z0 * ww : 0.f;
                float z1 = acc1[r] + bb; sacc[1][r] += (z1 > 0.f) ? z1 * ww : 0.f;
            }
        }
    }
    // column reduction over the 16 cols (lane bits 0..3)
    #pragma unroll
    for (int mt = 0; mt < 2; mt++) {
        #pragma unroll
        for (int r = 0; r < 4; r++) {
            float z = sacc[mt][r];
            z += __shfl_xor(z, 1);
            z += __shfl_xor(z, 2);
            z += __shfl_xor(z, 4);
            z += __shfl_xor(z, 8);
            sacc[mt][r] = z;
        }
    }
    if (col == 0) {
        #pragma unroll
        for (int mt = 0; mt < 2; mt++)
            #pragma unroll
            for (int r = 0; r < 4; r++)
                score[wave * 32 + mt * 16 + quad * 4 + r] = sacc[mt][r];
    }

    __syncthreads();

    // ---- phase 3: masked exp, denom^BETA, weighted sum, sigmoid ----
    const float dist = tdist * s_sumE;
    if (t < HH) {
        float e = (hidx[t] != tg) ? expf(score[t] + dist) : 0.f;
        eA[t]  = e;
        exs[t] = e * xsum[t];
    }
    __syncthreads();
    if (t < 64) {
        float s1 = eA[t]  + ((t + 64 < HH) ? eA[t + 64]  : 0.f);
        float s2 = exs[t] + ((t + 64 < HH) ? exs[t + 64] : 0.f);
        #pragma unroll
        for (int off = 32; off; off >>= 1) {
            s1 += __shfl_xor(s1, off);
            s2 += __shfl_xor(s2, off);
        }
        if (t == 0) {
            float pred = s2 / sqrtf(s1);   // exp_sum^0.5 (BETA=0.5)
            out[b] = 1.f / (1.f + expf(-pred));
        }
    }
}

extern "C" void kernel_launch(void* const* d_in, const int* in_sizes, int n_in,
                              void* d_out, int out_size, void* d_ws, size_t ws_size,
                              hipStream_t stream) {
    const int*   history         = (const int*)d_in[0];
    const int*   target          = (const int*)d_in[1];
    const int*   history_region  = (const int*)d_in[2];
    const int*   target_region   = (const int*)d_in[3];
    const float* target_distance = (const float*)d_in[4];
    const float* E_hist          = (const float*)d_in[5];
    const float* E_tgt           = (const float*)d_in[6];
    const float* E_reg           = (const float*)d_in[7];
    const float* E_dist          = (const float*)d_in[8];
    const float* W1              = (const float*)d_in[9];
    const float* b1              = (const float*)d_in[10];
    const float* w2              = (const float*)d_in[11];

    unsigned short* W1p = (unsigned short*)d_ws;  // 131072 B
    const int B = in_sizes[1];

    w1_pack<<<32, 256, 0, stream>>>(W1, W1p);
    nais_kernel<<<B, 256, 0, stream>>>(history, target, history_region, target_region,
                                       target_distance, E_hist, E_tgt, E_reg, E_dist,
                                       b1, w2, W1p, (float*)d_out);
}

// Round 6
// 198.932 us; speedup vs baseline: 1.3604x; 1.3604x over previous
//
#include <hip/hip_runtime.h>
#include <stdint.h>

typedef __attribute__((ext_vector_type(8))) short bf16x8;
typedef __attribute__((ext_vector_type(4))) float f32x4;

#define HH  100   // history length
#define DD  128   // embedding dim d
#define HID 256   // hidden width / concat dim

__device__ __forceinline__ unsigned short f2bf(float f) {
    unsigned int u = __float_as_uint(f);
    u += 0x7fffu + ((u >> 16) & 1u);   // round-to-nearest-even
    return (unsigned short)(u >> 16);
}

// async 1 KB global->LDS per wave: per-lane 16 B from g+lane*16, LDS at uniform base + lane*16
__device__ __forceinline__ void load_lds_1k(const void* g, void* l) {
    __builtin_amdgcn_global_load_lds((const __attribute__((address_space(1))) unsigned int*)g,
                                     (__attribute__((address_space(3))) unsigned int*)l,
                                     16, 0, 0);
}

// Pack W1 (256x256 f32, [n][k]) into MFMA B-fragment order, bf16.
// unit = (st*8+s)*64 + lane holds W1[st*16 + (lane&15)][s*32 + (lane>>4)*8 + j], j=0..7
__global__ void w1_pack(const float* __restrict__ W1, unsigned short* __restrict__ W1p) {
    int unit = blockIdx.x * 256 + threadIdx.x;   // 0..8191
    int lane = unit & 63;
    int s    = (unit >> 6) & 7;
    int st   = unit >> 9;
    int col  = lane & 15, quad = lane >> 4;
    const float* src = W1 + (size_t)(st * 16 + col) * HID + s * 32 + quad * 8;
    union { unsigned short u[8]; bf16x8 v; } o;
    #pragma unroll
    for (int j = 0; j < 8; j++) o.u[j] = f2bf(src[j]);
    *(bf16x8*)(W1p + (size_t)unit * 8) = o.v;
}

// NOTE: (256,2) is load-bearing. Anything tighter splits the unified VGPR/AGPR
// file too small (R3: 64, R5: 84 arch) and phase 1 spills ~200+ MB to scratch.
__global__ __launch_bounds__(256, 2) void nais_kernel(
    const int* __restrict__ history,           // [B,HH]
    const int* __restrict__ target,            // [B]
    const int* __restrict__ history_region,    // [B,HH]
    const int* __restrict__ target_region,     // [B]
    const float* __restrict__ target_distance, // [B]
    const float* __restrict__ E_hist,          // [item,128]
    const float* __restrict__ E_tgt,           // [item,128]
    const float* __restrict__ E_reg,           // [region,128]
    const float* __restrict__ E_dist,          // [16,128]
    const float* __restrict__ b1,              // [256]
    const float* __restrict__ w2,              // [256]
    const unsigned short* __restrict__ W1p,    // packed bf16 B-fragments (128 KB)
    float* __restrict__ out)                   // [B]
{
    // B-stage: 4 stages x 32 KB (4 st-strips each), double-buffered = 64 KB
    __shared__ __align__(16) unsigned short Bs[2][16384];
    __shared__ __align__(16) float tgts[HID];
    __shared__ __align__(16) float b1s[HID];
    __shared__ __align__(16) float w2s[HID];
    __shared__ float score[128];
    __shared__ float xsum[HH];
    __shared__ float eA[HH];
    __shared__ float exs[HH];
    __shared__ int hidx[HH];
    __shared__ int hreg[HH];
    __shared__ float s_sumE;

    const int b    = blockIdx.x;
    const int t    = threadIdx.x;
    const int lane = t & 63;
    const int wave = t >> 6;
    const int col  = lane & 15;
    const int quad = lane >> 4;

    const int   tg    = target[b];
    const float tdist = target_distance[b];

    // ---- phase 0: stage indices, tgt vector, b1/w2, sum(E_dist[0]) ----
    if (t < HH) {
        hidx[t] = history[b * HH + t];
        hreg[t] = history_region[b * HH + t];
    }
    if (wave == 1) {
        float v = E_dist[lane] + E_dist[64 + lane];
        #pragma unroll
        for (int off = 32; off; off >>= 1) v += __shfl_xor(v, off);
        if (lane == 0) s_sumE = v;
    }
    if (wave == 2) {
        float4 v;
        if (lane < 32) v = *(const float4*)(E_tgt + (size_t)tg * DD + lane * 4);
        else           v = *(const float4*)(E_reg + (size_t)target_region[b] * DD + (lane - 32) * 4);
        *(float4*)(tgts + lane * 4) = v;
    }
    if (wave == 3) {
        *(float4*)(b1s + lane * 4) = *(const float4*)(b1 + lane * 4);
        *(float4*)(w2s + lane * 4) = *(const float4*)(w2 + lane * 4);
    }
    __syncthreads();

    // issue stage-0 B load (async; overlaps the whole gather phase)
    {
        const char* g = (const char*)W1p + wave * 8192 + lane * 16;
        char*       l = (char*)&Bs[0][0] + wave * 8192;
        #pragma unroll
        for (int i = 0; i < 8; i++) load_lds_1k(g + i * 1024, l + i * 1024);
    }

    // ---- phase 1: gather E-rows directly into MFMA A-fragment layout ----
    // wave w owns rows [32w, 32w+32): m-tiles mt in {0,1}, row = 32w + mt*16 + col.
    // A-frag element: lane(col,quad), k = s*32 + quad*8 + j  (s<4: E_hist, s>=4: E_reg)
    bf16x8 afrag[2][8];
    float xs[2];
    #pragma unroll
    for (int mt = 0; mt < 2; mt++) {
        const int  row   = wave * 32 + mt * 16 + col;
        const bool valid = row < HH;
        const int  rc    = valid ? row : 0;
        const int  ih    = hidx[rc];
        const int  ir    = hreg[rc];
        const float* ph  = E_hist + (size_t)ih * DD + quad * 8;
        const float* pr  = E_reg  + (size_t)ir * DD + quad * 8;
        float acc = 0.f;
        #pragma unroll
        for (int s = 0; s < 8; s++) {
            const float* src = (s < 4) ? (ph + s * 32) : (pr + (s - 4) * 32);
            float4 v0 = {0.f, 0.f, 0.f, 0.f}, v1 = {0.f, 0.f, 0.f, 0.f};
            if (valid) { v0 = *(const float4*)src; v1 = *(const float4*)(src + 4); }
            const float* tp = tgts + s * 32 + quad * 8;      // broadcast across cols
            float4 t0 = *(const float4*)tp, t1 = *(const float4*)(tp + 4);
            float x0 = v0.x * t0.x, x1 = v0.y * t0.y, x2 = v0.z * t0.z, x3 = v0.w * t0.w;
            float x4 = v1.x * t1.x, x5 = v1.y * t1.y, x6 = v1.z * t1.z, x7 = v1.w * t1.w;
            acc += (x0 + x1) + (x2 + x3) + ((x4 + x5) + (x6 + x7));
            union { unsigned short u[8]; bf16x8 v; } fb;
            fb.u[0] = f2bf(x0); fb.u[1] = f2bf(x1); fb.u[2] = f2bf(x2); fb.u[3] = f2bf(x3);
            fb.u[4] = f2bf(x4); fb.u[5] = f2bf(x5); fb.u[6] = f2bf(x6); fb.u[7] = f2bf(x7);
            afrag[mt][s] = fb.v;
        }
        xs[mt] = acc;
        // scheduling fence: cap in-flight gather loads at 16 float4 (64 VGPRs)
        asm volatile("" ::: "memory");
    }
    // xsum[row] = sum over k: reduce across the 4 quads (lane bits 4,5)
    #pragma unroll
    for (int mt = 0; mt < 2; mt++) {
        float v = xs[mt];
        v += __shfl_xor(v, 16);
        v += __shfl_xor(v, 32);
        const int row = wave * 32 + mt * 16 + col;
        if (quad == 0 && row < HH) xsum[row] = v;
    }

    // ---- phase 2: score = relu(X @ W1^T + b1) . w2 via MFMA, B staged thru LDS ----
    // stage k holds st in {4k..4k+3}; barrier-per-stage double buffer:
    //   barrier (stage-k data visible) -> issue(k+1) into buf[(k+1)&1] -> compute(k)
    float sacc[2][4] = {};
    #pragma unroll 1
    for (int k = 0; k < 4; k++) {
        __syncthreads();
        if (k < 3) {
            const char* g = (const char*)W1p + (k + 1) * 32768 + wave * 8192 + lane * 16;
            char*       l = (char*)&Bs[(k + 1) & 1][0] + wave * 8192;
            #pragma unroll
            for (int i = 0; i < 8; i++) load_lds_1k(g + i * 1024, l + i * 1024);
        }
        const unsigned short* buf = &Bs[k & 1][0];
        #pragma unroll
        for (int sti = 0; sti < 4; sti++) {
            const int st = k * 4 + sti;
            const float bb = b1s[st * 16 + col];
            const float ww = w2s[st * 16 + col];
            f32x4 acc0 = {0.f, 0.f, 0.f, 0.f};
            f32x4 acc1 = {0.f, 0.f, 0.f, 0.f};
            #pragma unroll
            for (int s = 0; s < 8; s++) {
                bf16x8 bfrag = *(const bf16x8*)(buf + ((sti * 8 + s) * 64 + lane) * 8);
                acc0 = __builtin_amdgcn_mfma_f32_16x16x32_bf16(afrag[0][s], bfrag, acc0, 0, 0, 0);
                acc1 = __builtin_amdgcn_mfma_f32_16x16x32_bf16(afrag[1][s], bfrag, acc1, 0, 0, 0);
            }
            #pragma unroll
            for (int r = 0; r < 4; r++) {
                float z0 = acc0[r] + bb; sacc[0][r] += (z0 > 0.f) ? z0 * ww : 0.f;
                float z1 = acc1[r] + bb; sacc[1][r] += (z1 > 0.f) ? z1 * ww : 0.f;
            }
        }
    }
    // column reduction over the 16 cols (lane bits 0..3)
    #pragma unroll
    for (int mt = 0; mt < 2; mt++) {
        #pragma unroll
        for (int r = 0; r < 4; r++) {
            float z = sacc[mt][r];
            z += __shfl_xor(z, 1);
            z += __shfl_xor(z, 2);
            z += __shfl_xor(z, 4);
            z += __shfl_xor(z, 8);
            sacc[mt][r] = z;
        }
    }
    if (col == 0) {
        #pragma unroll
        for (int mt = 0; mt < 2; mt++)
            #pragma unroll
            for (int r = 0; r < 4; r++)
                score[wave * 32 + mt * 16 + quad * 4 + r] = sacc[mt][r];
    }

    __syncthreads();

    // ---- phase 3: masked exp, denom^BETA, weighted sum, sigmoid ----
    const float dist = tdist * s_sumE;
    if (t < HH) {
        float e = (hidx[t] != tg) ? expf(score[t] + dist) : 0.f;
        eA[t]  = e;
        exs[t] = e * xsum[t];
    }
    __syncthreads();
    if (t < 64) {
        float s1 = eA[t]  + ((t + 64 < HH) ? eA[t + 64]  : 0.f);
        float s2 = exs[t] + ((t + 64 < HH) ? exs[t + 64] : 0.f);
        #pragma unroll
        for (int off = 32; off; off >>= 1) {
            s1 += __shfl_xor(s1, off);
            s2 += __shfl_xor(s2, off);
        }
        if (t == 0) {
            float pred = s2 / sqrtf(s1);   // exp_sum^0.5 (BETA=0.5)
            out[b] = 1.f / (1.f + expf(-pred));
        }
    }
}

extern "C" void kernel_launch(void* const* d_in, const int* in_sizes, int n_in,
                              void* d_out, int out_size, void* d_ws, size_t ws_size,
                              hipStream_t stream) {
    const int*   history         = (const int*)d_in[0];
    const int*   target          = (const int*)d_in[1];
    const int*   history_region  = (const int*)d_in[2];
    const int*   target_region   = (const int*)d_in[3];
    const float* target_distance = (const float*)d_in[4];
    const float* E_hist          = (const float*)d_in[5];
    const float* E_tgt           = (const float*)d_in[6];
    const float* E_reg           = (const float*)d_in[7];
    const float* E_dist          = (const float*)d_in[8];
    const float* W1              = (const float*)d_in[9];
    const float* b1              = (const float*)d_in[10];
    const float* w2              = (const float*)d_in[11];

    unsigned short* W1p = (unsigned short*)d_ws;  // 131072 B
    const int B = in_sizes[1];

    w1_pack<<<32, 256, 0, stream>>>(W1, W1p);
    nais_kernel<<<B, 256, 0, stream>>>(history, target, history_region, target_region,
                                       target_distance, E_hist, E_tgt, E_reg, E_dist,
                                       b1, w2, W1p, (float*)d_out);
}